// Round 3
// baseline (583.739 us; speedup 1.0000x reference)
//
#include <hip/hip_runtime.h>
#include <cstdint>

// ---------------------------------------------------------------------------
// BotRGCN round 10: de-fuse + coalesce the CSR pipeline.
//  Round-9 lesson: fused k_pre (hist+embed) = 84 us, stall-bound (VALU 15%,
//  917 GB/s) with ~19.5 MB of partial-sector traffic from 611K strided 4B
//  cntmat stores; fusion destroyed per-phase observability.
//  Changes:
//   - k_pre: embed only, uint4 (16B) plane stores.
//   - k_hist: histogram only, writes count matrix ROW-major [blk][bin]
//     (coalesced full lines).
//   - k_transpose (LDS 32x33 tiles): [blk][bin] -> [bin][blk] for the scan,
//     and scanned [bin][blk] -> [blk][bin] so binscatter reads coalesced rows.
//   - k_binscatter: cursor base loads now coalesced.
//  Everything else (scan, bincsr, gather, GEMMs) unchanged.
// ---------------------------------------------------------------------------

typedef short bf16x8 __attribute__((ext_vector_type(8)));
typedef float f32x4  __attribute__((ext_vector_type(4)));

__device__ __forceinline__ unsigned short f2bf(float f) {
    unsigned int u = __builtin_bit_cast(unsigned int, f);
    u += 0x7fff + ((u >> 16) & 1);          // RNE
    return (unsigned short)(u >> 16);
}
__device__ __forceinline__ float bf2f(unsigned short h) {
    unsigned int u = ((unsigned int)h) << 16;
    return __builtin_bit_cast(float, u);
}
__device__ __forceinline__ float lo16f(unsigned int u) {
    return __builtin_bit_cast(float, u << 16);
}
__device__ __forceinline__ float hi16f(unsigned int u) {
    return __builtin_bit_cast(float, u & 0xffff0000u);
}

__device__ __forceinline__ void gload_lds16(const void* g, void* l) {
    __builtin_amdgcn_global_load_lds(
        (const __attribute__((address_space(1))) void*)g,
        (__attribute__((address_space(3))) void*)l, 16, 0, 0);
}

// ---- feature pre-embed, one thread = 8 dims of one node, uint4 stores ----
__global__ __launch_bounds__(256) void k_pre(
    const float* __restrict__ x,
    const float* __restrict__ Wnum, const float* __restrict__ bnum,
    const float* __restrict__ Wcat, const float* __restrict__ bcat,
    unsigned short* __restrict__ hi, unsigned short* __restrict__ lo, int N)
{
    int gid = blockIdx.x * 256 + threadIdx.x;
    if (gid >= N * 16) return;
    int n = gid >> 4, k8 = (gid & 15) << 3;
    const float* xr = x + n * 8;
    float xv[8];
    #pragma unroll
    for (int p = 0; p < 8; ++p) xv[p] = xr[p];
    unsigned hw[4], lw[4];
    #pragma unroll
    for (int q = 0; q < 8; ++q) {
        int k = k8 + q;
        float acc;
        if (k < 64) {
            acc = bnum[k];
            #pragma unroll
            for (int p = 0; p < 5; ++p) acc += xv[p] * Wnum[p * 64 + k];
        } else {
            int kk = k - 64;
            acc = bcat[kk];
            #pragma unroll
            for (int p = 0; p < 3; ++p) acc += xv[5 + p] * Wcat[p * 64 + kk];
        }
        float v = acc >= 0.f ? acc : 0.01f * acc;
        unsigned short h = f2bf(v);
        unsigned short l = f2bf(v - bf2f(h));
        if (q & 1) {
            hw[q >> 1] |= (unsigned)h << 16;
            lw[q >> 1] |= (unsigned)l << 16;
        } else {
            hw[q >> 1] = h;
            lw[q >> 1] = l;
        }
    }
    uint4 ho, loo;
    ho.x = hw[0]; ho.y = hw[1]; ho.z = hw[2]; ho.w = hw[3];
    loo.x = lw[0]; loo.y = lw[1]; loo.z = lw[2]; loo.w = lw[3];
    ((uint4*)hi)[gid] = ho;
    ((uint4*)lo)[gid] = loo;
}

// ---- pass A: per-block bin histogram, ROW-major (coalesced) output ----
__global__ __launch_bounds__(256) void k_hist(
    const int* __restrict__ ei, const int* __restrict__ et,
    int* __restrict__ cntmatT, int E, int N, int NBINS)
{
    __shared__ int hist[1024];
    const int t = threadIdx.x, blk = blockIdx.x;
    for (int i = t; i < NBINS; i += 256) hist[i] = 0;
    __syncthreads();
    #pragma unroll
    for (int j = 0; j < 8; ++j) {
        int e = blk * 2048 + j * 256 + t;
        if (e < E) atomicAdd(&hist[(et[e] * N + ei[E + e]) >> 8], 1);
    }
    __syncthreads();
    for (int i = t; i < NBINS; i += 256)
        cntmatT[(size_t)blk * NBINS + i] = hist[i];
}

// ---- LDS-tiled int transpose: dst[c*R + r] = src[r*C + c] ----
__global__ __launch_bounds__(256) void k_transpose(
    const int* __restrict__ src, int* __restrict__ dst, int R, int C)
{
    __shared__ int tile[32][33];
    int ctiles = (C + 31) >> 5;
    int bx = blockIdx.x % ctiles;
    int by = blockIdx.x / ctiles;
    int tc = threadIdx.x & 31, tr = threadIdx.x >> 5;
    int c0 = bx * 32, r0 = by * 32;
    #pragma unroll
    for (int i = 0; i < 32; i += 8) {
        int r = r0 + tr + i, c = c0 + tc;
        if (r < R && c < C) tile[tr + i][tc] = src[(size_t)r * C + c];
    }
    __syncthreads();
    #pragma unroll
    for (int i = 0; i < 32; i += 8) {
        int r = r0 + tc;
        int c = c0 + tr + i;
        if (r < R && c < C) dst[(size_t)c * R + r] = tile[tc][tr + i];
    }
}

// ---- weight split+transpose ----
struct WArgs {
    const float* W[8];
    unsigned short* hi[8];
    unsigned short* lo[8];
};
__global__ __launch_bounds__(256) void k_wsplit(WArgs a)
{
    int part = blockIdx.y;
    int idx = blockIdx.x * 256 + threadIdx.x;
    int n = idx >> 7, k = idx & 127;
    float v = a.W[part][(size_t)k * 128 + n];
    unsigned short h = f2bf(v);
    a.hi[part][(size_t)n * 128 + k] = h;
    a.lo[part][(size_t)n * 128 + k] = f2bf(v - bf2f(h));
}

// ---- scans over the bin-major count matrix ----
__global__ __launch_bounds__(256) void k_scan1(
    const int* __restrict__ src, int* __restrict__ dst,
    int* __restrict__ bsum, int n)
{
    __shared__ int s[256];
    int t = threadIdx.x;
    int i = blockIdx.x * 256 + t;
    int v = (i < n) ? src[i] : 0;
    s[t] = v;
    __syncthreads();
    #pragma unroll
    for (int d = 1; d < 256; d <<= 1) {
        int add = (t >= d) ? s[t - d] : 0;
        __syncthreads();
        s[t] += add;
        __syncthreads();
    }
    if (i < n) dst[i] = s[t] - v;
    if (t == 255) bsum[blockIdx.x] = s[255];
}

__global__ __launch_bounds__(1024) void k_scan2(int* __restrict__ bsum, int nb)
{
    __shared__ int s[1024];
    int t = threadIdx.x;
    int carry = 0;
    for (int base = 0; base < nb; base += 1024) {
        int i = base + t;
        int v = (i < nb) ? bsum[i] : 0;
        s[t] = v;
        __syncthreads();
        #pragma unroll
        for (int d = 1; d < 1024; d <<= 1) {
            int add = (t >= d) ? s[t - d] : 0;
            __syncthreads();
            s[t] += add;
            __syncthreads();
        }
        if (i < nb) bsum[i] = carry + s[t] - v;
        carry += s[1023];
        __syncthreads();
    }
}

__global__ __launch_bounds__(256) void k_scan3(
    int* __restrict__ dst, const int* __restrict__ bsum, int n)
{
    int i = blockIdx.x * 256 + threadIdx.x;
    if (i < n) dst[i] += bsum[blockIdx.x];
}

// ---- pass C: scatter edges into bin-contiguous ebuf (LDS cursors) ----
// cursor base loads now coalesced from blk-major cntscanT
__global__ __launch_bounds__(256) void k_binscatter(
    const int* __restrict__ ei, const int* __restrict__ et,
    const int* __restrict__ cntscanT, int* __restrict__ ebuf,
    int E, int N, int NBINS)
{
    __shared__ int base[1024];
    const int t = threadIdx.x;
    const int blk = blockIdx.x;
    for (int i = t; i < NBINS; i += 256)
        base[i] = cntscanT[(size_t)blk * NBINS + i];
    __syncthreads();
    #pragma unroll
    for (int j = 0; j < 8; ++j) {
        int e = blk * 2048 + j * 256 + t;
        if (e < E) {
            unsigned src = (unsigned)ei[e];
            int seg = et[e] * N + ei[E + e];
            int pos = atomicAdd(&base[seg >> 8], 1);     // LDS atomic
            ebuf[pos] = (int)(((unsigned)(seg & 255) << 24) | src);
        }
    }
}

// ---- pass D: per-bin exact CSR (256 segs/bin, LDS count + scan) ----
__global__ __launch_bounds__(256) void k_bincsr(
    const int* __restrict__ cntscan, const int* __restrict__ ebuf,
    int* __restrict__ deg, int* __restrict__ off, int* __restrict__ esrc,
    int E, int nseg, int NBLK, int NBINS)
{
    __shared__ int cnt[256];
    __shared__ int pfx[256];
    __shared__ int cur[256];
    const int b = blockIdx.x;
    const int t = threadIdx.x;
    const int est = cntscan[(size_t)b * NBLK];
    const int een = (b + 1 < NBINS) ? cntscan[(size_t)(b + 1) * NBLK] : E;
    cnt[t] = 0;
    __syncthreads();
    for (int e = est + t; e < een; e += 256)
        atomicAdd(&cnt[((unsigned)ebuf[e]) >> 24], 1);
    __syncthreads();
    int v = cnt[t];
    pfx[t] = v;
    __syncthreads();
    #pragma unroll
    for (int d = 1; d < 256; d <<= 1) {
        int add = (t >= d) ? pfx[t - d] : 0;
        __syncthreads();
        pfx[t] += add;
        __syncthreads();
    }
    int o = est + pfx[t] - v;
    int seg = b * 256 + t;
    if (seg < nseg) { deg[seg] = v; off[seg] = o; }
    cur[t] = o;
    __syncthreads();
    for (int e = est + t; e < een; e += 256) {
        unsigned u = (unsigned)ebuf[e];
        int p = atomicAdd(&cur[u >> 24], 1);             // LDS atomic
        esrc[p] = (int)(u & 0xffffffu);
    }
}

// ---- mean aggregation, bf16 hi plane, quarter-wave rows ----
__global__ __launch_bounds__(256) void k_gather(
    const unsigned short* __restrict__ h_hi,
    const int* __restrict__ esrc,
    const int* __restrict__ off, const int* __restrict__ deg,
    unsigned short* __restrict__ a_hi, int nseg)
{
    int i = blockIdx.x * 8 + (threadIdx.x >> 5);
    if (i >= nseg) return;
    int l32 = threadIdx.x & 31;
    int q = l32 >> 4;
    int l16 = l32 & 15;
    int cnt = deg[i], st = off[i];
    const uint4* hp = (const uint4*)h_hi;
    float a0 = 0.f, a1 = 0.f, a2 = 0.f, a3 = 0.f;
    float a4 = 0.f, a5 = 0.f, a6 = 0.f, a7 = 0.f;
    int e = q;
    for (; e + 6 < cnt; e += 8) {
        int i0 = esrc[st + e + 0];
        int i1 = esrc[st + e + 2];
        int i2 = esrc[st + e + 4];
        int i3 = esrc[st + e + 6];
        uint4 u0 = hp[(size_t)i0 * 16 + l16];
        uint4 u1 = hp[(size_t)i1 * 16 + l16];
        uint4 u2 = hp[(size_t)i2 * 16 + l16];
        uint4 u3 = hp[(size_t)i3 * 16 + l16];
        a0 += lo16f(u0.x); a1 += hi16f(u0.x); a2 += lo16f(u0.y); a3 += hi16f(u0.y);
        a4 += lo16f(u0.z); a5 += hi16f(u0.z); a6 += lo16f(u0.w); a7 += hi16f(u0.w);
        a0 += lo16f(u1.x); a1 += hi16f(u1.x); a2 += lo16f(u1.y); a3 += hi16f(u1.y);
        a4 += lo16f(u1.z); a5 += hi16f(u1.z); a6 += lo16f(u1.w); a7 += hi16f(u1.w);
        a0 += lo16f(u2.x); a1 += hi16f(u2.x); a2 += lo16f(u2.y); a3 += hi16f(u2.y);
        a4 += lo16f(u2.z); a5 += hi16f(u2.z); a6 += lo16f(u2.w); a7 += hi16f(u2.w);
        a0 += lo16f(u3.x); a1 += hi16f(u3.x); a2 += lo16f(u3.y); a3 += hi16f(u3.y);
        a4 += lo16f(u3.z); a5 += hi16f(u3.z); a6 += lo16f(u3.w); a7 += hi16f(u3.w);
    }
    for (; e < cnt; e += 2) {
        uint4 u = hp[(size_t)esrc[st + e] * 16 + l16];
        a0 += lo16f(u.x); a1 += hi16f(u.x); a2 += lo16f(u.y); a3 += hi16f(u.y);
        a4 += lo16f(u.z); a5 += hi16f(u.z); a6 += lo16f(u.w); a7 += hi16f(u.w);
    }
    a0 += __shfl_xor(a0, 16, 64);
    a1 += __shfl_xor(a1, 16, 64);
    a2 += __shfl_xor(a2, 16, 64);
    a3 += __shfl_xor(a3, 16, 64);
    a4 += __shfl_xor(a4, 16, 64);
    a5 += __shfl_xor(a5, 16, 64);
    a6 += __shfl_xor(a6, 16, 64);
    a7 += __shfl_xor(a7, 16, 64);
    if (q == 0) {
        float inv = 1.0f / (float)(cnt > 1 ? cnt : 1);
        uint4 o;
        o.x = (unsigned int)f2bf(a0 * inv) | ((unsigned int)f2bf(a1 * inv) << 16);
        o.y = (unsigned int)f2bf(a2 * inv) | ((unsigned int)f2bf(a3 * inv) << 16);
        o.z = (unsigned int)f2bf(a4 * inv) | ((unsigned int)f2bf(a5 * inv) << 16);
        o.w = (unsigned int)f2bf(a6 * inv) | ((unsigned int)f2bf(a7 * inv) << 16);
        ((uint4*)a_hi)[(size_t)i * 16 + l16] = o;
    }
}

// ---- pipelined split-bf16 MFMA GEMM ----
struct GArgs {
    const unsigned short* A_hi[3];
    const unsigned short* A_lo[3];
    const unsigned short* B_hi[3];   // transposed [n][k]
    const unsigned short* B_lo[3];
    int alo[3];
    int blo[3];
    const float* bias;
    const float* prelu;
    float* Cf;                       // if non-null: fp32 output
    unsigned short* C_hi;
    unsigned short* C_lo;
    int M;
    int P;
};

__global__ __launch_bounds__(256) void k_mgemm(GArgs g)
{
    __shared__ unsigned short lds[2][32 * 512];   // 2 x 32 KB
    const int t = threadIdx.x;
    const int w = t >> 6, lane = t & 63;
    const int laneL = lane & 15, laneH = lane >> 4;
    const int wi = w >> 1, wj = w & 1;
    const int m0 = blockIdx.x * 128;
    const int Mm1 = g.M - 1;
    const int S = g.P * 4;

    f32x4 acc[4][4];
    #pragma unroll
    for (int a = 0; a < 4; ++a)
        #pragma unroll
        for (int b = 0; b < 4; ++b)
            acc[a][b] = (f32x4){0.f, 0.f, 0.f, 0.f};

    auto stage = [&](int s, unsigned short* buf) {
        int p = s >> 2, koff = (s & 3) * 32;
        const unsigned short* tp[4];
        tp[0] = g.A_hi[p];
        tp[1] = g.alo[p] ? g.A_lo[p] : nullptr;
        tp[2] = g.B_hi[p];
        tp[3] = g.blo[p] ? g.B_lo[p] : nullptr;
        #pragma unroll
        for (int c = 0; c < 8; ++c) {
            int chunk = w + c * 4;            // 0..31
            int slot = chunk >> 3, j = chunk & 7;
            const unsigned short* plane = tp[slot];
            if (!plane) continue;
            int rc = j * 16 + laneL;
            int row = (slot < 2) ? (m0 + rc <= Mm1 ? m0 + rc : Mm1) : rc;
            const unsigned short* gp = plane + (size_t)row * 128 + koff + laneH * 8;
            gload_lds16(gp, &buf[(slot * 8 + j) * 512]);
        }
    };

    stage(0, lds[0]);
    for (int s = 0; s < S; ++s) {
        unsigned short* cur = lds[s & 1];
        unsigned short* nxt = lds[(s & 1) ^ 1];
        __syncthreads();                      // drains stage(s); frees nxt
        if (s + 1 < S) stage(s + 1, nxt);     // overlaps with compute below
        int p = s >> 2;
        const bool hasAlo = g.alo[p] != 0;
        const bool hasBlo = g.blo[p] != 0;
        const bf16x8* fr = (const bf16x8*)cur;
        bf16x8 ah[4], al[4], bh[4], bl[4];
        #pragma unroll
        for (int mi = 0; mi < 4; ++mi)
            ah[mi] = fr[(0 + wi * 4 + mi) * 64 + lane];
        if (hasAlo) {
            #pragma unroll
            for (int mi = 0; mi < 4; ++mi)
                al[mi] = fr[(8 + wi * 4 + mi) * 64 + lane];
        }
        #pragma unroll
        for (int nj = 0; nj < 4; ++nj)
            bh[nj] = fr[(16 + wj * 4 + nj) * 64 + lane];
        if (hasBlo) {
            #pragma unroll
            for (int nj = 0; nj < 4; ++nj)
                bl[nj] = fr[(24 + wj * 4 + nj) * 64 + lane];
        }
        #pragma unroll
        for (int mi = 0; mi < 4; ++mi)
            #pragma unroll
            for (int nj = 0; nj < 4; ++nj) {
                acc[mi][nj] = __builtin_amdgcn_mfma_f32_16x16x32_bf16(
                    ah[mi], bh[nj], acc[mi][nj], 0, 0, 0);
                if (hasBlo)
                    acc[mi][nj] = __builtin_amdgcn_mfma_f32_16x16x32_bf16(
                        ah[mi], bl[nj], acc[mi][nj], 0, 0, 0);
                if (hasAlo)
                    acc[mi][nj] = __builtin_amdgcn_mfma_f32_16x16x32_bf16(
                        al[mi], bh[nj], acc[mi][nj], 0, 0, 0);
            }
    }

    // ---- epilogue: acc -> LDS (C layout) -> coalesced stores ----
    const bool hasPrelu = (g.prelu != nullptr);
    float bv[4], av[4];
    #pragma unroll
    for (int nj = 0; nj < 4; ++nj) {
        int col = wj * 64 + nj * 16 + laneL;
        bv[nj] = g.bias[col];
        av[nj] = hasPrelu ? g.prelu[col] : 0.f;
    }

    if (g.Cf) {
        float* lf = (float*)&lds[0][0];       // 128x128 f32 = 64 KB
        __syncthreads();
        #pragma unroll
        for (int nj = 0; nj < 4; ++nj) {
            int col = wj * 64 + nj * 16 + laneL;
            #pragma unroll
            for (int mi = 0; mi < 4; ++mi)
                #pragma unroll
                for (int r = 0; r < 4; ++r) {
                    int row = wi * 64 + mi * 16 + laneH * 4 + r;
                    float v = acc[mi][nj][r] + bv[nj];
                    lf[row * 128 + col] = v;
                }
        }
        __syncthreads();
        const uint4* lsrc = (const uint4*)lf;
        #pragma unroll
        for (int it = 0; it < 16; ++it) {
            int idx = it * 256 + t;          // 4096 uint4
            int row = idx >> 5, c = idx & 31;
            int m = m0 + row;
            if (m < g.M)
                ((uint4*)(g.Cf + (size_t)m * 128))[c] = lsrc[idx];
        }
    } else {
        unsigned short* lp = &lds[0][0];     // 128x128 ushort = 32 KB
        // hi pass
        __syncthreads();
        #pragma unroll
        for (int nj = 0; nj < 4; ++nj) {
            int col = wj * 64 + nj * 16 + laneL;
            #pragma unroll
            for (int mi = 0; mi < 4; ++mi)
                #pragma unroll
                for (int r = 0; r < 4; ++r) {
                    int row = wi * 64 + mi * 16 + laneH * 4 + r;
                    float v = acc[mi][nj][r] + bv[nj];
                    if (hasPrelu) v = v >= 0.f ? v : av[nj] * v;
                    lp[row * 128 + col] = f2bf(v);
                }
        }
        __syncthreads();
        {
            const uint4* lsrc = (const uint4*)lp;
            #pragma unroll
            for (int it = 0; it < 8; ++it) {
                int idx = it * 256 + t;      // 2048 uint4
                int row = idx >> 4, c = idx & 15;
                int m = m0 + row;
                if (m < g.M)
                    ((uint4*)(g.C_hi + (size_t)m * 128))[c] = lsrc[idx];
            }
        }
        // lo pass
        __syncthreads();
        #pragma unroll
        for (int nj = 0; nj < 4; ++nj) {
            int col = wj * 64 + nj * 16 + laneL;
            #pragma unroll
            for (int mi = 0; mi < 4; ++mi)
                #pragma unroll
                for (int r = 0; r < 4; ++r) {
                    int row = wi * 64 + mi * 16 + laneH * 4 + r;
                    float v = acc[mi][nj][r] + bv[nj];
                    if (hasPrelu) v = v >= 0.f ? v : av[nj] * v;
                    unsigned short h = f2bf(v);
                    lp[row * 128 + col] = f2bf(v - bf2f(h));
                }
        }
        __syncthreads();
        {
            const uint4* lsrc = (const uint4*)lp;
            #pragma unroll
            for (int it = 0; it < 8; ++it) {
                int idx = it * 256 + t;
                int row = idx >> 4, c = idx & 15;
                int m = m0 + row;
                if (m < g.M)
                    ((uint4*)(g.C_lo + (size_t)m * 128))[c] = lsrc[idx];
            }
        }
    }
}

extern "C" void kernel_launch(void* const* d_in, const int* in_sizes, int n_in,
                              void* d_out, int out_size, void* d_ws, size_t ws_size,
                              hipStream_t stream) {
    const float* x      = (const float*)d_in[0];
    const int*   ei     = (const int*)d_in[1];
    const int*   et     = (const int*)d_in[2];
    const float* Wnum   = (const float*)d_in[3];
    const float* bnum   = (const float*)d_in[4];
    const float* Wcat   = (const float*)d_in[5];
    const float* bcat   = (const float*)d_in[6];
    const float* Win    = (const float*)d_in[7];
    const float* bin    = (const float*)d_in[8];
    const float* pa     = (const float*)d_in[9];
    const float* Wrel1  = (const float*)d_in[10];
    const float* Wroot1 = (const float*)d_in[11];
    const float* brg1   = (const float*)d_in[12];
    const float* Wrel2  = (const float*)d_in[13];
    const float* Wroot2 = (const float*)d_in[14];
    const float* brg2   = (const float*)d_in[15];
    const float* Wcls   = (const float*)d_in[16];
    const float* bcls   = (const float*)d_in[17];
    float* out = (float*)d_out;

    const int N = in_sizes[0] / 8;
    const int E = in_sizes[1] / 2;
    const int nseg = 2 * N;
    const size_t NH = (size_t)N * 128;

    const int NBLK  = (E + 2047) / 2048;        // edge blocks (782)
    const int NBINS = (nseg + 255) / 256;       // coarse bins (782)
    const long long L = (long long)NBINS * NBLK;

    char* w = (char*)d_ws;
    unsigned short* h0_hi = (unsigned short*)w;  w += NH * 2;
    unsigned short* h0_lo = (unsigned short*)w;  w += NH * 2;
    unsigned short* agg_hi = (unsigned short*)w; w += 2 * NH * 2;
    int* deg      = (int*)w;  w += (size_t)nseg * 4;
    int* off      = (int*)w;  w += (size_t)nseg * 4;
    int* cntmatT  = (int*)w;  w += (size_t)L * 4;   // [blk][bin]
    int* cntmat   = (int*)w;  w += (size_t)L * 4;   // [bin][blk]
    int* cntscan  = (int*)w;  w += (size_t)L * 4;   // [bin][blk] scanned
    int* cntscanT = (int*)w;  w += (size_t)L * 4;   // [blk][bin] scanned
    int* esrc     = (int*)w;  w += (size_t)E * 4;
    int* bsum     = (int*)w;  w += 4096 * 4;
    unsigned short* wplanes = (unsigned short*)w;  w += 8 * 2 * 16384 * 2;

    unsigned short* hp_hi = agg_hi;
    unsigned short* hp_lo = agg_hi + NH;
    unsigned short* h1_hi = (unsigned short*)d_out;
    unsigned short* h1_lo = h1_hi + NH;
    unsigned short* h2_hi = h0_hi;
    unsigned short* h2_lo = h0_lo;
    int* ebuf = (int*)d_out;   // E ints; dead before h1 is written (layer-1 GEMM)

    unsigned short* whi[8];
    unsigned short* wlo[8];
    for (int i = 0; i < 8; ++i) {
        whi[i] = wplanes + (size_t)i * 2 * 16384;
        wlo[i] = whi[i] + 16384;
    }

    {
        WArgs a;
        a.W[0] = Win;   a.W[1] = Wroot1; a.W[2] = Wrel1; a.W[3] = Wrel1 + 16384;
        a.W[4] = Wroot2; a.W[5] = Wrel2; a.W[6] = Wrel2 + 16384; a.W[7] = Wcls;
        for (int i = 0; i < 8; ++i) { a.hi[i] = whi[i]; a.lo[i] = wlo[i]; }
        k_wsplit<<<dim3(64, 8), 256, 0, stream>>>(a);
    }

    const int gm = (N + 127) / 128;
    const int gg = (nseg + 7) / 8;

    // embed (standalone)
    k_pre<<<(N * 16 + 255) / 256, 256, 0, stream>>>(
        x, Wnum, bnum, Wcat, bcat, hp_hi, hp_lo, N);

    // CSR pipeline
    k_hist<<<NBLK, 256, 0, stream>>>(ei, et, cntmatT, E, N, NBINS);

    const int rt = (NBLK + 31) / 32, ct = (NBINS + 31) / 32;
    k_transpose<<<rt * ct, 256, 0, stream>>>(cntmatT, cntmat, NBLK, NBINS);

    const int nb1 = (int)((L + 255) / 256);
    k_scan1<<<nb1, 256, 0, stream>>>(cntmat, cntscan, bsum, (int)L);
    k_scan2<<<1, 1024, 0, stream>>>(bsum, nb1);
    k_scan3<<<nb1, 256, 0, stream>>>(cntscan, bsum, (int)L);

    k_transpose<<<ct * rt, 256, 0, stream>>>(cntscan, cntscanT, NBINS, NBLK);

    k_binscatter<<<NBLK, 256, 0, stream>>>(ei, et, cntscanT, ebuf, E, N, NBINS);
    k_bincsr<<<NBINS, 256, 0, stream>>>(cntscan, ebuf, deg, off, esrc, E, nseg, NBLK, NBINS);

    // embed GEMM
    {
        GArgs g = {};
        g.A_hi[0] = hp_hi; g.A_lo[0] = hp_lo; g.alo[0] = 1; g.blo[0] = 1;
        g.B_hi[0] = whi[0]; g.B_lo[0] = wlo[0];
        g.bias = bin; g.prelu = pa;
        g.Cf = nullptr; g.C_hi = h0_hi; g.C_lo = h0_lo;
        g.M = N; g.P = 1;
        k_mgemm<<<gm, 256, 0, stream>>>(g);
    }
    // layer 1
    k_gather<<<gg, 256, 0, stream>>>(h0_hi, esrc, off, deg, agg_hi, nseg);
    {
        GArgs g = {};
        g.A_hi[0] = h0_hi;       g.A_lo[0] = h0_lo;  g.alo[0] = 1; g.blo[0] = 1;
        g.A_hi[1] = agg_hi;      g.alo[1] = 0;       g.blo[1] = 0;
        g.A_hi[2] = agg_hi + NH; g.alo[2] = 0;       g.blo[2] = 0;
        g.B_hi[0] = whi[1]; g.B_lo[0] = wlo[1];
        g.B_hi[1] = whi[2]; g.B_lo[1] = wlo[2];
        g.B_hi[2] = whi[3]; g.B_lo[2] = wlo[3];
        g.bias = brg1; g.prelu = nullptr;
        g.Cf = nullptr; g.C_hi = h1_hi; g.C_lo = h1_lo;
        g.M = N; g.P = 3;
        k_mgemm<<<gm, 256, 0, stream>>>(g);
    }
    // layer 2
    k_gather<<<gg, 256, 0, stream>>>(h1_hi, esrc, off, deg, agg_hi, nseg);
    {
        GArgs g = {};
        g.A_hi[0] = h1_hi;       g.A_lo[0] = h1_lo;  g.alo[0] = 1; g.blo[0] = 1;
        g.A_hi[1] = agg_hi;      g.alo[1] = 0;       g.blo[1] = 0;
        g.A_hi[2] = agg_hi + NH; g.alo[2] = 0;       g.blo[2] = 0;
        g.B_hi[0] = whi[4]; g.B_lo[0] = wlo[4];
        g.B_hi[1] = whi[5]; g.B_lo[1] = wlo[5];
        g.B_hi[2] = whi[6]; g.B_lo[2] = wlo[6];
        g.bias = brg2; g.prelu = nullptr;
        g.Cf = nullptr; g.C_hi = h2_hi; g.C_lo = h2_lo;
        g.M = N; g.P = 3;
        k_mgemm<<<gm, 256, 0, stream>>>(g);
    }
    // classifier
    {
        GArgs g = {};
        g.A_hi[0] = h2_hi; g.A_lo[0] = h2_lo; g.alo[0] = 1; g.blo[0] = 1;
        g.B_hi[0] = whi[7]; g.B_lo[0] = wlo[7];
        g.bias = bcls; g.prelu = nullptr;
        g.Cf = out; g.C_hi = nullptr; g.C_lo = nullptr;
        g.M = N; g.P = 1;
        k_mgemm<<<gm, 256, 0, stream>>>(g);
    }
}

// Round 4
// 484.516 us; speedup vs baseline: 1.2048x; 1.2048x over previous
//
#include <hip/hip_runtime.h>
#include <cstdint>

// ---------------------------------------------------------------------------
// BotRGCN round 11: fix the embed regression; keep atomic-free CSR.
//  Round-10 lesson: 8-dim/thread embed with per-q branch -> 16 exec-masked
//  scalar-load blocks per thread, latency-serialized (119 us @ 445 GB/s,
//  VALU 9.5%). Fix: 4 dims/thread (quad never straddles k=64 -> thread-
//  uniform branch), float4 loads for x/W/bias, ushort4 stores. ~8 VMEM
//  ops/thread, 3.2M threads of TLP.
//  CSR pipeline (hist -> transpose -> scan -> transpose -> binscatter ->
//  bincsr), gather, GEMMs unchanged from round 10.
// ---------------------------------------------------------------------------

typedef short bf16x8 __attribute__((ext_vector_type(8)));
typedef float f32x4  __attribute__((ext_vector_type(4)));

__device__ __forceinline__ unsigned short f2bf(float f) {
    unsigned int u = __builtin_bit_cast(unsigned int, f);
    u += 0x7fff + ((u >> 16) & 1);          // RNE
    return (unsigned short)(u >> 16);
}
__device__ __forceinline__ float bf2f(unsigned short h) {
    unsigned int u = ((unsigned int)h) << 16;
    return __builtin_bit_cast(float, u);
}
__device__ __forceinline__ float lo16f(unsigned int u) {
    return __builtin_bit_cast(float, u << 16);
}
__device__ __forceinline__ float hi16f(unsigned int u) {
    return __builtin_bit_cast(float, u & 0xffff0000u);
}

__device__ __forceinline__ void gload_lds16(const void* g, void* l) {
    __builtin_amdgcn_global_load_lds(
        (const __attribute__((address_space(1))) void*)g,
        (__attribute__((address_space(3))) void*)l, 16, 0, 0);
}

// ---- feature pre-embed: one thread = 4 aligned dims of one node ----
// Thread-uniform branch (quad of 4 dims never straddles the 64 boundary);
// all loads are float4; stores ushort4 (8B) coalesced.
__global__ __launch_bounds__(256) void k_pre(
    const float* __restrict__ x,
    const float* __restrict__ Wnum, const float* __restrict__ bnum,
    const float* __restrict__ Wcat, const float* __restrict__ bcat,
    unsigned short* __restrict__ hi, unsigned short* __restrict__ lo, int N)
{
    int gid = blockIdx.x * 256 + threadIdx.x;
    if (gid >= N * 32) return;
    int n = gid >> 5, kq = (gid & 31) << 2;   // kq in {0,4,...,124}
    const float4* xr = (const float4*)(x + (size_t)n * 8);
    float4 x0 = xr[0];
    float4 x1 = xr[1];
    float4 a;
    if (kq < 64) {
        a = *(const float4*)(bnum + kq);
        float4 w0 = *(const float4*)(Wnum + 0 * 64 + kq);
        float4 w1 = *(const float4*)(Wnum + 1 * 64 + kq);
        float4 w2 = *(const float4*)(Wnum + 2 * 64 + kq);
        float4 w3 = *(const float4*)(Wnum + 3 * 64 + kq);
        float4 w4 = *(const float4*)(Wnum + 4 * 64 + kq);
        a.x += x0.x*w0.x + x0.y*w1.x + x0.z*w2.x + x0.w*w3.x + x1.x*w4.x;
        a.y += x0.x*w0.y + x0.y*w1.y + x0.z*w2.y + x0.w*w3.y + x1.x*w4.y;
        a.z += x0.x*w0.z + x0.y*w1.z + x0.z*w2.z + x0.w*w3.z + x1.x*w4.z;
        a.w += x0.x*w0.w + x0.y*w1.w + x0.z*w2.w + x0.w*w3.w + x1.x*w4.w;
    } else {
        int kk = kq - 64;
        a = *(const float4*)(bcat + kk);
        float4 w0 = *(const float4*)(Wcat + 0 * 64 + kk);
        float4 w1 = *(const float4*)(Wcat + 1 * 64 + kk);
        float4 w2 = *(const float4*)(Wcat + 2 * 64 + kk);
        a.x += x1.y*w0.x + x1.z*w1.x + x1.w*w2.x;
        a.y += x1.y*w0.y + x1.z*w1.y + x1.w*w2.y;
        a.z += x1.y*w0.z + x1.z*w1.z + x1.w*w2.z;
        a.w += x1.y*w0.w + x1.z*w1.w + x1.w*w2.w;
    }
    float v0 = a.x >= 0.f ? a.x : 0.01f * a.x;
    float v1 = a.y >= 0.f ? a.y : 0.01f * a.y;
    float v2 = a.z >= 0.f ? a.z : 0.01f * a.z;
    float v3 = a.w >= 0.f ? a.w : 0.01f * a.w;
    ushort4 h, l;
    h.x = f2bf(v0); l.x = f2bf(v0 - bf2f(h.x));
    h.y = f2bf(v1); l.y = f2bf(v1 - bf2f(h.y));
    h.z = f2bf(v2); l.z = f2bf(v2 - bf2f(h.z));
    h.w = f2bf(v3); l.w = f2bf(v3 - bf2f(h.w));
    ((ushort4*)hi)[gid] = h;
    ((ushort4*)lo)[gid] = l;
}

// ---- pass A: per-block bin histogram, ROW-major (coalesced) output ----
__global__ __launch_bounds__(256) void k_hist(
    const int* __restrict__ ei, const int* __restrict__ et,
    int* __restrict__ cntmatT, int E, int N, int NBINS)
{
    __shared__ int hist[1024];
    const int t = threadIdx.x, blk = blockIdx.x;
    for (int i = t; i < NBINS; i += 256) hist[i] = 0;
    __syncthreads();
    #pragma unroll
    for (int j = 0; j < 8; ++j) {
        int e = blk * 2048 + j * 256 + t;
        if (e < E) atomicAdd(&hist[(et[e] * N + ei[E + e]) >> 8], 1);
    }
    __syncthreads();
    for (int i = t; i < NBINS; i += 256)
        cntmatT[(size_t)blk * NBINS + i] = hist[i];
}

// ---- LDS-tiled int transpose: dst[c*R + r] = src[r*C + c] ----
__global__ __launch_bounds__(256) void k_transpose(
    const int* __restrict__ src, int* __restrict__ dst, int R, int C)
{
    __shared__ int tile[32][33];
    int ctiles = (C + 31) >> 5;
    int bx = blockIdx.x % ctiles;
    int by = blockIdx.x / ctiles;
    int tc = threadIdx.x & 31, tr = threadIdx.x >> 5;
    int c0 = bx * 32, r0 = by * 32;
    #pragma unroll
    for (int i = 0; i < 32; i += 8) {
        int r = r0 + tr + i, c = c0 + tc;
        if (r < R && c < C) tile[tr + i][tc] = src[(size_t)r * C + c];
    }
    __syncthreads();
    #pragma unroll
    for (int i = 0; i < 32; i += 8) {
        int r = r0 + tc;
        int c = c0 + tr + i;
        if (r < R && c < C) dst[(size_t)c * R + r] = tile[tc][tr + i];
    }
}

// ---- weight split+transpose ----
struct WArgs {
    const float* W[8];
    unsigned short* hi[8];
    unsigned short* lo[8];
};
__global__ __launch_bounds__(256) void k_wsplit(WArgs a)
{
    int part = blockIdx.y;
    int idx = blockIdx.x * 256 + threadIdx.x;
    int n = idx >> 7, k = idx & 127;
    float v = a.W[part][(size_t)k * 128 + n];
    unsigned short h = f2bf(v);
    a.hi[part][(size_t)n * 128 + k] = h;
    a.lo[part][(size_t)n * 128 + k] = f2bf(v - bf2f(h));
}

// ---- scans over the bin-major count matrix ----
__global__ __launch_bounds__(256) void k_scan1(
    const int* __restrict__ src, int* __restrict__ dst,
    int* __restrict__ bsum, int n)
{
    __shared__ int s[256];
    int t = threadIdx.x;
    int i = blockIdx.x * 256 + t;
    int v = (i < n) ? src[i] : 0;
    s[t] = v;
    __syncthreads();
    #pragma unroll
    for (int d = 1; d < 256; d <<= 1) {
        int add = (t >= d) ? s[t - d] : 0;
        __syncthreads();
        s[t] += add;
        __syncthreads();
    }
    if (i < n) dst[i] = s[t] - v;
    if (t == 255) bsum[blockIdx.x] = s[255];
}

__global__ __launch_bounds__(1024) void k_scan2(int* __restrict__ bsum, int nb)
{
    __shared__ int s[1024];
    int t = threadIdx.x;
    int carry = 0;
    for (int base = 0; base < nb; base += 1024) {
        int i = base + t;
        int v = (i < nb) ? bsum[i] : 0;
        s[t] = v;
        __syncthreads();
        #pragma unroll
        for (int d = 1; d < 1024; d <<= 1) {
            int add = (t >= d) ? s[t - d] : 0;
            __syncthreads();
            s[t] += add;
            __syncthreads();
        }
        if (i < nb) bsum[i] = carry + s[t] - v;
        carry += s[1023];
        __syncthreads();
    }
}

__global__ __launch_bounds__(256) void k_scan3(
    int* __restrict__ dst, const int* __restrict__ bsum, int n)
{
    int i = blockIdx.x * 256 + threadIdx.x;
    if (i < n) dst[i] += bsum[blockIdx.x];
}

// ---- pass C: scatter edges into bin-contiguous ebuf (LDS cursors) ----
__global__ __launch_bounds__(256) void k_binscatter(
    const int* __restrict__ ei, const int* __restrict__ et,
    const int* __restrict__ cntscanT, int* __restrict__ ebuf,
    int E, int N, int NBINS)
{
    __shared__ int base[1024];
    const int t = threadIdx.x;
    const int blk = blockIdx.x;
    for (int i = t; i < NBINS; i += 256)
        base[i] = cntscanT[(size_t)blk * NBINS + i];
    __syncthreads();
    #pragma unroll
    for (int j = 0; j < 8; ++j) {
        int e = blk * 2048 + j * 256 + t;
        if (e < E) {
            unsigned src = (unsigned)ei[e];
            int seg = et[e] * N + ei[E + e];
            int pos = atomicAdd(&base[seg >> 8], 1);     // LDS atomic
            ebuf[pos] = (int)(((unsigned)(seg & 255) << 24) | src);
        }
    }
}

// ---- pass D: per-bin exact CSR (256 segs/bin, LDS count + scan) ----
__global__ __launch_bounds__(256) void k_bincsr(
    const int* __restrict__ cntscan, const int* __restrict__ ebuf,
    int* __restrict__ deg, int* __restrict__ off, int* __restrict__ esrc,
    int E, int nseg, int NBLK, int NBINS)
{
    __shared__ int cnt[256];
    __shared__ int pfx[256];
    __shared__ int cur[256];
    const int b = blockIdx.x;
    const int t = threadIdx.x;
    const int est = cntscan[(size_t)b * NBLK];
    const int een = (b + 1 < NBINS) ? cntscan[(size_t)(b + 1) * NBLK] : E;
    cnt[t] = 0;
    __syncthreads();
    for (int e = est + t; e < een; e += 256)
        atomicAdd(&cnt[((unsigned)ebuf[e]) >> 24], 1);
    __syncthreads();
    int v = cnt[t];
    pfx[t] = v;
    __syncthreads();
    #pragma unroll
    for (int d = 1; d < 256; d <<= 1) {
        int add = (t >= d) ? pfx[t - d] : 0;
        __syncthreads();
        pfx[t] += add;
        __syncthreads();
    }
    int o = est + pfx[t] - v;
    int seg = b * 256 + t;
    if (seg < nseg) { deg[seg] = v; off[seg] = o; }
    cur[t] = o;
    __syncthreads();
    for (int e = est + t; e < een; e += 256) {
        unsigned u = (unsigned)ebuf[e];
        int p = atomicAdd(&cur[u >> 24], 1);             // LDS atomic
        esrc[p] = (int)(u & 0xffffffu);
    }
}

// ---- mean aggregation, bf16 hi plane, quarter-wave rows ----
__global__ __launch_bounds__(256) void k_gather(
    const unsigned short* __restrict__ h_hi,
    const int* __restrict__ esrc,
    const int* __restrict__ off, const int* __restrict__ deg,
    unsigned short* __restrict__ a_hi, int nseg)
{
    int i = blockIdx.x * 8 + (threadIdx.x >> 5);
    if (i >= nseg) return;
    int l32 = threadIdx.x & 31;
    int q = l32 >> 4;
    int l16 = l32 & 15;
    int cnt = deg[i], st = off[i];
    const uint4* hp = (const uint4*)h_hi;
    float a0 = 0.f, a1 = 0.f, a2 = 0.f, a3 = 0.f;
    float a4 = 0.f, a5 = 0.f, a6 = 0.f, a7 = 0.f;
    int e = q;
    for (; e + 6 < cnt; e += 8) {
        int i0 = esrc[st + e + 0];
        int i1 = esrc[st + e + 2];
        int i2 = esrc[st + e + 4];
        int i3 = esrc[st + e + 6];
        uint4 u0 = hp[(size_t)i0 * 16 + l16];
        uint4 u1 = hp[(size_t)i1 * 16 + l16];
        uint4 u2 = hp[(size_t)i2 * 16 + l16];
        uint4 u3 = hp[(size_t)i3 * 16 + l16];
        a0 += lo16f(u0.x); a1 += hi16f(u0.x); a2 += lo16f(u0.y); a3 += hi16f(u0.y);
        a4 += lo16f(u0.z); a5 += hi16f(u0.z); a6 += lo16f(u0.w); a7 += hi16f(u0.w);
        a0 += lo16f(u1.x); a1 += hi16f(u1.x); a2 += lo16f(u1.y); a3 += hi16f(u1.y);
        a4 += lo16f(u1.z); a5 += hi16f(u1.z); a6 += lo16f(u1.w); a7 += hi16f(u1.w);
        a0 += lo16f(u2.x); a1 += hi16f(u2.x); a2 += lo16f(u2.y); a3 += hi16f(u2.y);
        a4 += lo16f(u2.z); a5 += hi16f(u2.z); a6 += lo16f(u2.w); a7 += hi16f(u2.w);
        a0 += lo16f(u3.x); a1 += hi16f(u3.x); a2 += lo16f(u3.y); a3 += hi16f(u3.y);
        a4 += lo16f(u3.z); a5 += hi16f(u3.z); a6 += lo16f(u3.w); a7 += hi16f(u3.w);
    }
    for (; e < cnt; e += 2) {
        uint4 u = hp[(size_t)esrc[st + e] * 16 + l16];
        a0 += lo16f(u.x); a1 += hi16f(u.x); a2 += lo16f(u.y); a3 += hi16f(u.y);
        a4 += lo16f(u.z); a5 += hi16f(u.z); a6 += lo16f(u.w); a7 += hi16f(u.w);
    }
    a0 += __shfl_xor(a0, 16, 64);
    a1 += __shfl_xor(a1, 16, 64);
    a2 += __shfl_xor(a2, 16, 64);
    a3 += __shfl_xor(a3, 16, 64);
    a4 += __shfl_xor(a4, 16, 64);
    a5 += __shfl_xor(a5, 16, 64);
    a6 += __shfl_xor(a6, 16, 64);
    a7 += __shfl_xor(a7, 16, 64);
    if (q == 0) {
        float inv = 1.0f / (float)(cnt > 1 ? cnt : 1);
        uint4 o;
        o.x = (unsigned int)f2bf(a0 * inv) | ((unsigned int)f2bf(a1 * inv) << 16);
        o.y = (unsigned int)f2bf(a2 * inv) | ((unsigned int)f2bf(a3 * inv) << 16);
        o.z = (unsigned int)f2bf(a4 * inv) | ((unsigned int)f2bf(a5 * inv) << 16);
        o.w = (unsigned int)f2bf(a6 * inv) | ((unsigned int)f2bf(a7 * inv) << 16);
        ((uint4*)a_hi)[(size_t)i * 16 + l16] = o;
    }
}

// ---- pipelined split-bf16 MFMA GEMM ----
struct GArgs {
    const unsigned short* A_hi[3];
    const unsigned short* A_lo[3];
    const unsigned short* B_hi[3];   // transposed [n][k]
    const unsigned short* B_lo[3];
    int alo[3];
    int blo[3];
    const float* bias;
    const float* prelu;
    float* Cf;                       // if non-null: fp32 output
    unsigned short* C_hi;
    unsigned short* C_lo;
    int M;
    int P;
};

__global__ __launch_bounds__(256) void k_mgemm(GArgs g)
{
    __shared__ unsigned short lds[2][32 * 512];   // 2 x 32 KB
    const int t = threadIdx.x;
    const int w = t >> 6, lane = t & 63;
    const int laneL = lane & 15, laneH = lane >> 4;
    const int wi = w >> 1, wj = w & 1;
    const int m0 = blockIdx.x * 128;
    const int Mm1 = g.M - 1;
    const int S = g.P * 4;

    f32x4 acc[4][4];
    #pragma unroll
    for (int a = 0; a < 4; ++a)
        #pragma unroll
        for (int b = 0; b < 4; ++b)
            acc[a][b] = (f32x4){0.f, 0.f, 0.f, 0.f};

    auto stage = [&](int s, unsigned short* buf) {
        int p = s >> 2, koff = (s & 3) * 32;
        const unsigned short* tp[4];
        tp[0] = g.A_hi[p];
        tp[1] = g.alo[p] ? g.A_lo[p] : nullptr;
        tp[2] = g.B_hi[p];
        tp[3] = g.blo[p] ? g.B_lo[p] : nullptr;
        #pragma unroll
        for (int c = 0; c < 8; ++c) {
            int chunk = w + c * 4;            // 0..31
            int slot = chunk >> 3, j = chunk & 7;
            const unsigned short* plane = tp[slot];
            if (!plane) continue;
            int rc = j * 16 + laneL;
            int row = (slot < 2) ? (m0 + rc <= Mm1 ? m0 + rc : Mm1) : rc;
            const unsigned short* gp = plane + (size_t)row * 128 + koff + laneH * 8;
            gload_lds16(gp, &buf[(slot * 8 + j) * 512]);
        }
    };

    stage(0, lds[0]);
    for (int s = 0; s < S; ++s) {
        unsigned short* cur = lds[s & 1];
        unsigned short* nxt = lds[(s & 1) ^ 1];
        __syncthreads();                      // drains stage(s); frees nxt
        if (s + 1 < S) stage(s + 1, nxt);     // overlaps with compute below
        int p = s >> 2;
        const bool hasAlo = g.alo[p] != 0;
        const bool hasBlo = g.blo[p] != 0;
        const bf16x8* fr = (const bf16x8*)cur;
        bf16x8 ah[4], al[4], bh[4], bl[4];
        #pragma unroll
        for (int mi = 0; mi < 4; ++mi)
            ah[mi] = fr[(0 + wi * 4 + mi) * 64 + lane];
        if (hasAlo) {
            #pragma unroll
            for (int mi = 0; mi < 4; ++mi)
                al[mi] = fr[(8 + wi * 4 + mi) * 64 + lane];
        }
        #pragma unroll
        for (int nj = 0; nj < 4; ++nj)
            bh[nj] = fr[(16 + wj * 4 + nj) * 64 + lane];
        if (hasBlo) {
            #pragma unroll
            for (int nj = 0; nj < 4; ++nj)
                bl[nj] = fr[(24 + wj * 4 + nj) * 64 + lane];
        }
        #pragma unroll
        for (int mi = 0; mi < 4; ++mi)
            #pragma unroll
            for (int nj = 0; nj < 4; ++nj) {
                acc[mi][nj] = __builtin_amdgcn_mfma_f32_16x16x32_bf16(
                    ah[mi], bh[nj], acc[mi][nj], 0, 0, 0);
                if (hasBlo)
                    acc[mi][nj] = __builtin_amdgcn_mfma_f32_16x16x32_bf16(
                        ah[mi], bl[nj], acc[mi][nj], 0, 0, 0);
                if (hasAlo)
                    acc[mi][nj] = __builtin_amdgcn_mfma_f32_16x16x32_bf16(
                        al[mi], bh[nj], acc[mi][nj], 0, 0, 0);
            }
    }

    // ---- epilogue: acc -> LDS (C layout) -> coalesced stores ----
    const bool hasPrelu = (g.prelu != nullptr);
    float bv[4], av[4];
    #pragma unroll
    for (int nj = 0; nj < 4; ++nj) {
        int col = wj * 64 + nj * 16 + laneL;
        bv[nj] = g.bias[col];
        av[nj] = hasPrelu ? g.prelu[col] : 0.f;
    }

    if (g.Cf) {
        float* lf = (float*)&lds[0][0];       // 128x128 f32 = 64 KB
        __syncthreads();
        #pragma unroll
        for (int nj = 0; nj < 4; ++nj) {
            int col = wj * 64 + nj * 16 + laneL;
            #pragma unroll
            for (int mi = 0; mi < 4; ++mi)
                #pragma unroll
                for (int r = 0; r < 4; ++r) {
                    int row = wi * 64 + mi * 16 + laneH * 4 + r;
                    float v = acc[mi][nj][r] + bv[nj];
                    lf[row * 128 + col] = v;
                }
        }
        __syncthreads();
        const uint4* lsrc = (const uint4*)lf;
        #pragma unroll
        for (int it = 0; it < 16; ++it) {
            int idx = it * 256 + t;          // 4096 uint4
            int row = idx >> 5, c = idx & 31;
            int m = m0 + row;
            if (m < g.M)
                ((uint4*)(g.Cf + (size_t)m * 128))[c] = lsrc[idx];
        }
    } else {
        unsigned short* lp = &lds[0][0];     // 128x128 ushort = 32 KB
        // hi pass
        __syncthreads();
        #pragma unroll
        for (int nj = 0; nj < 4; ++nj) {
            int col = wj * 64 + nj * 16 + laneL;
            #pragma unroll
            for (int mi = 0; mi < 4; ++mi)
                #pragma unroll
                for (int r = 0; r < 4; ++r) {
                    int row = wi * 64 + mi * 16 + laneH * 4 + r;
                    float v = acc[mi][nj][r] + bv[nj];
                    if (hasPrelu) v = v >= 0.f ? v : av[nj] * v;
                    lp[row * 128 + col] = f2bf(v);
                }
        }
        __syncthreads();
        {
            const uint4* lsrc = (const uint4*)lp;
            #pragma unroll
            for (int it = 0; it < 8; ++it) {
                int idx = it * 256 + t;      // 2048 uint4
                int row = idx >> 4, c = idx & 15;
                int m = m0 + row;
                if (m < g.M)
                    ((uint4*)(g.C_hi + (size_t)m * 128))[c] = lsrc[idx];
            }
        }
        // lo pass
        __syncthreads();
        #pragma unroll
        for (int nj = 0; nj < 4; ++nj) {
            int col = wj * 64 + nj * 16 + laneL;
            #pragma unroll
            for (int mi = 0; mi < 4; ++mi)
                #pragma unroll
                for (int r = 0; r < 4; ++r) {
                    int row = wi * 64 + mi * 16 + laneH * 4 + r;
                    float v = acc[mi][nj][r] + bv[nj];
                    if (hasPrelu) v = v >= 0.f ? v : av[nj] * v;
                    unsigned short h = f2bf(v);
                    lp[row * 128 + col] = f2bf(v - bf2f(h));
                }
        }
        __syncthreads();
        {
            const uint4* lsrc = (const uint4*)lp;
            #pragma unroll
            for (int it = 0; it < 8; ++it) {
                int idx = it * 256 + t;
                int row = idx >> 4, c = idx & 15;
                int m = m0 + row;
                if (m < g.M)
                    ((uint4*)(g.C_lo + (size_t)m * 128))[c] = lsrc[idx];
            }
        }
    }
}

extern "C" void kernel_launch(void* const* d_in, const int* in_sizes, int n_in,
                              void* d_out, int out_size, void* d_ws, size_t ws_size,
                              hipStream_t stream) {
    const float* x      = (const float*)d_in[0];
    const int*   ei     = (const int*)d_in[1];
    const int*   et     = (const int*)d_in[2];
    const float* Wnum   = (const float*)d_in[3];
    const float* bnum   = (const float*)d_in[4];
    const float* Wcat   = (const float*)d_in[5];
    const float* bcat   = (const float*)d_in[6];
    const float* Win    = (const float*)d_in[7];
    const float* bin    = (const float*)d_in[8];
    const float* pa     = (const float*)d_in[9];
    const float* Wrel1  = (const float*)d_in[10];
    const float* Wroot1 = (const float*)d_in[11];
    const float* brg1   = (const float*)d_in[12];
    const float* Wrel2  = (const float*)d_in[13];
    const float* Wroot2 = (const float*)d_in[14];
    const float* brg2   = (const float*)d_in[15];
    const float* Wcls   = (const float*)d_in[16];
    const float* bcls   = (const float*)d_in[17];
    float* out = (float*)d_out;

    const int N = in_sizes[0] / 8;
    const int E = in_sizes[1] / 2;
    const int nseg = 2 * N;
    const size_t NH = (size_t)N * 128;

    const int NBLK  = (E + 2047) / 2048;        // edge blocks (782)
    const int NBINS = (nseg + 255) / 256;       // coarse bins (782)
    const long long L = (long long)NBINS * NBLK;

    char* w = (char*)d_ws;
    unsigned short* h0_hi = (unsigned short*)w;  w += NH * 2;
    unsigned short* h0_lo = (unsigned short*)w;  w += NH * 2;
    unsigned short* agg_hi = (unsigned short*)w; w += 2 * NH * 2;
    int* deg      = (int*)w;  w += (size_t)nseg * 4;
    int* off      = (int*)w;  w += (size_t)nseg * 4;
    int* cntmatT  = (int*)w;  w += (size_t)L * 4;   // [blk][bin]
    int* cntmat   = (int*)w;  w += (size_t)L * 4;   // [bin][blk]
    int* cntscan  = (int*)w;  w += (size_t)L * 4;   // [bin][blk] scanned
    int* cntscanT = (int*)w;  w += (size_t)L * 4;   // [blk][bin] scanned
    int* esrc     = (int*)w;  w += (size_t)E * 4;
    int* bsum     = (int*)w;  w += 4096 * 4;
    unsigned short* wplanes = (unsigned short*)w;  w += 8 * 2 * 16384 * 2;

    unsigned short* hp_hi = agg_hi;
    unsigned short* hp_lo = agg_hi + NH;
    unsigned short* h1_hi = (unsigned short*)d_out;
    unsigned short* h1_lo = h1_hi + NH;
    unsigned short* h2_hi = h0_hi;
    unsigned short* h2_lo = h0_lo;
    int* ebuf = (int*)d_out;   // E ints; dead before h1 is written (layer-1 GEMM)

    unsigned short* whi[8];
    unsigned short* wlo[8];
    for (int i = 0; i < 8; ++i) {
        whi[i] = wplanes + (size_t)i * 2 * 16384;
        wlo[i] = whi[i] + 16384;
    }

    {
        WArgs a;
        a.W[0] = Win;   a.W[1] = Wroot1; a.W[2] = Wrel1; a.W[3] = Wrel1 + 16384;
        a.W[4] = Wroot2; a.W[5] = Wrel2; a.W[6] = Wrel2 + 16384; a.W[7] = Wcls;
        for (int i = 0; i < 8; ++i) { a.hi[i] = whi[i]; a.lo[i] = wlo[i]; }
        k_wsplit<<<dim3(64, 8), 256, 0, stream>>>(a);
    }

    const int gm = (N + 127) / 128;
    const int gg = (nseg + 7) / 8;

    // embed (standalone, 4 dims/thread, vector loads)
    k_pre<<<(N * 32 + 255) / 256, 256, 0, stream>>>(
        x, Wnum, bnum, Wcat, bcat, hp_hi, hp_lo, N);

    // CSR pipeline
    k_hist<<<NBLK, 256, 0, stream>>>(ei, et, cntmatT, E, N, NBINS);

    const int rt = (NBLK + 31) / 32, ct = (NBINS + 31) / 32;
    k_transpose<<<rt * ct, 256, 0, stream>>>(cntmatT, cntmat, NBLK, NBINS);

    const int nb1 = (int)((L + 255) / 256);
    k_scan1<<<nb1, 256, 0, stream>>>(cntmat, cntscan, bsum, (int)L);
    k_scan2<<<1, 1024, 0, stream>>>(bsum, nb1);
    k_scan3<<<nb1, 256, 0, stream>>>(cntscan, bsum, (int)L);

    k_transpose<<<ct * rt, 256, 0, stream>>>(cntscan, cntscanT, NBINS, NBLK);

    k_binscatter<<<NBLK, 256, 0, stream>>>(ei, et, cntscanT, ebuf, E, N, NBINS);
    k_bincsr<<<NBINS, 256, 0, stream>>>(cntscan, ebuf, deg, off, esrc, E, nseg, NBLK, NBINS);

    // embed GEMM
    {
        GArgs g = {};
        g.A_hi[0] = hp_hi; g.A_lo[0] = hp_lo; g.alo[0] = 1; g.blo[0] = 1;
        g.B_hi[0] = whi[0]; g.B_lo[0] = wlo[0];
        g.bias = bin; g.prelu = pa;
        g.Cf = nullptr; g.C_hi = h0_hi; g.C_lo = h0_lo;
        g.M = N; g.P = 1;
        k_mgemm<<<gm, 256, 0, stream>>>(g);
    }
    // layer 1
    k_gather<<<gg, 256, 0, stream>>>(h0_hi, esrc, off, deg, agg_hi, nseg);
    {
        GArgs g = {};
        g.A_hi[0] = h0_hi;       g.A_lo[0] = h0_lo;  g.alo[0] = 1; g.blo[0] = 1;
        g.A_hi[1] = agg_hi;      g.alo[1] = 0;       g.blo[1] = 0;
        g.A_hi[2] = agg_hi + NH; g.alo[2] = 0;       g.blo[2] = 0;
        g.B_hi[0] = whi[1]; g.B_lo[0] = wlo[1];
        g.B_hi[1] = whi[2]; g.B_lo[1] = wlo[2];
        g.B_hi[2] = whi[3]; g.B_lo[2] = wlo[3];
        g.bias = brg1; g.prelu = nullptr;
        g.Cf = nullptr; g.C_hi = h1_hi; g.C_lo = h1_lo;
        g.M = N; g.P = 3;
        k_mgemm<<<gm, 256, 0, stream>>>(g);
    }
    // layer 2
    k_gather<<<gg, 256, 0, stream>>>(h1_hi, esrc, off, deg, agg_hi, nseg);
    {
        GArgs g = {};
        g.A_hi[0] = h1_hi;       g.A_lo[0] = h1_lo;  g.alo[0] = 1; g.blo[0] = 1;
        g.A_hi[1] = agg_hi;      g.alo[1] = 0;       g.blo[1] = 0;
        g.A_hi[2] = agg_hi + NH; g.alo[2] = 0;       g.blo[2] = 0;
        g.B_hi[0] = whi[4]; g.B_lo[0] = wlo[4];
        g.B_hi[1] = whi[5]; g.B_lo[1] = wlo[5];
        g.B_hi[2] = whi[6]; g.B_lo[2] = wlo[6];
        g.bias = brg2; g.prelu = nullptr;
        g.Cf = nullptr; g.C_hi = h2_hi; g.C_lo = h2_lo;
        g.M = N; g.P = 3;
        k_mgemm<<<gm, 256, 0, stream>>>(g);
    }
    // classifier
    {
        GArgs g = {};
        g.A_hi[0] = h2_hi; g.A_lo[0] = h2_lo; g.alo[0] = 1; g.blo[0] = 1;
        g.B_hi[0] = whi[7]; g.B_lo[0] = wlo[7];
        g.bias = bcls; g.prelu = nullptr;
        g.Cf = out; g.C_hi = nullptr; g.C_lo = nullptr;
        g.M = N; g.P = 1;
        k_mgemm<<<gm, 256, 0, stream>>>(g);
    }
}